// Round 16
// baseline (147.965 us; speedup 1.0000x reference)
//
#include <hip/hip_runtime.h>

typedef float  f32x4 __attribute__((ext_vector_type(4)));
typedef short  s16x8 __attribute__((ext_vector_type(8)));
typedef unsigned short u16x4 __attribute__((ext_vector_type(4)));

#define MFMA16(a,b,c) __builtin_amdgcn_mfma_f32_16x16x32_bf16(a,b,c,0,0,0)

// sizes: B=128, S=20, T=19, E=H=512, G=2048, V=10000 (padded 10112)
#define PRED_ELEMS 24320000ull

__device__ __forceinline__ unsigned short f2bf(float f){
  unsigned u = __builtin_bit_cast(unsigned, f);
  u += 0x7fffu + ((u >> 16) & 1u);
  return (unsigned short)(u >> 16);
}
__device__ __forceinline__ float sigf(float x){ return 1.0f/(1.0f + __expf(-x)); }
__device__ __forceinline__ float tanh_(float x){
  x = fminf(15.0f, fmaxf(-15.0f, x));
  float e = __expf(2.0f*x);
  return (e - 1.0f) / (e + 1.0f);
}
__device__ __forceinline__ s16x8 ld8(const unsigned short* p){
  return *reinterpret_cast<const s16x8*>(p);
}
__device__ __forceinline__ void gload_lds16(const unsigned short* src, unsigned short* dst){
  __builtin_amdgcn_global_load_lds(
      (const __attribute__((address_space(1))) void*)src,
      (__attribute__((address_space(3))) void*)dst, 16, 0, 0);
}

// ---------------- K0: stable descending sort by length, tail outputs, counter init ----------------
__global__ void k0_sort(const int* __restrict__ length, const int* __restrict__ captions,
                        float* __restrict__ out, int* __restrict__ sortp,
                        int* __restrict__ nactp, unsigned int* __restrict__ cnt4k)
{
  __shared__ int sl[128], sdl[128], ssi[128];
  int tid = threadIdx.x;
  for (int k = tid; k < 1024; k += 128) cnt4k[k] = 0u;   // claim + flags + fcflag (4 KB)
  if (tid < 128) sl[tid] = length[tid];
  __syncthreads();
  if (tid < 128){
    int l = sl[tid];
    int rank = 0;
    for (int j = 0; j < 128; ++j){
      int lj = sl[j];
      rank += (lj > l) || (lj == l && j < tid);
    }
    sortp[rank] = tid;
    ssi[rank] = tid;   sdl[rank] = l - 1;
  }
  __syncthreads();
  if (tid < 20){
    int c = 0;
    for (int r = 0; r < 128; ++r) c += (sdl[r] >= tid);
    nactp[tid] = c;
  }
  if (tid < 128){
    const size_t P = PRED_ELEMS;
    int si = ssi[tid];
    for (int t = 0; t < 20; ++t) out[P + tid*20 + t] = (float)captions[si*20 + t];
    out[P + 2560 + tid] = (float)sdl[tid];
    out[P + 2688 + tid] = (float)si;
  }
}

// ---------------- K1: bf16 conversion / gather / zero-init (4-elem units) ----------------
__device__ __forceinline__ void cvt4(unsigned short* dst, const float* src, int u){
  f32x4 v = *reinterpret_cast<const f32x4*>(src + (size_t)u*4);
  u16x4 o;
  o[0]=f2bf(v[0]); o[1]=f2bf(v[1]); o[2]=f2bf(v[2]); o[3]=f2bf(v[3]);
  *reinterpret_cast<u16x4*>(dst + (size_t)u*4) = o;
}

__global__ void k1_convert(const float* __restrict__ images, const int* __restrict__ captions,
    const float* __restrict__ emb, const float* __restrict__ wih, const float* __restrict__ whh,
    const float* __restrict__ bih, const float* __restrict__ bhh, const float* __restrict__ fcw,
    const int* __restrict__ sortp,
    unsigned short* __restrict__ wihb, unsigned short* __restrict__ whhb,
    unsigned short* __restrict__ fcwb, float* __restrict__ biasp,
    unsigned short* __restrict__ xseq, unsigned short* __restrict__ hseq,
    unsigned short* __restrict__ hloc)
{
  const int U0 = 262144;      // W_ih  2048*512/4
  const int U1 = 262144;      // W_hh
  const int U2 = 1294336;     // fc_w padded 10112*512/4
  const int U3 = 512;         // bias 2048/4
  const int U4 = 327680;      // xseq 20*128*512/4
  const int U5 = 16384;       // hseq slot 0 (unused by fc; kept deterministic)
  const int U6 = 16384;       // hloc slot 0 per XCD (8 x 16 x 512)
  const int total = U0+U1+U2+U3+U4+U5+U6;
  for (int i = blockIdx.x*blockDim.x + threadIdx.x; i < total; i += gridDim.x*blockDim.x){
    int j = i;
    if (j < U0){ cvt4(wihb, wih, j); continue; }
    j -= U0;
    if (j < U1){ cvt4(whhb, whh, j); continue; }
    j -= U1;
    if (j < U2){
      int row = j >> 7;               // (j*4)/512
      if (row < 10000) cvt4(fcwb, fcw, j);
      else { u16x4 z = {0,0,0,0}; *reinterpret_cast<u16x4*>(fcwb + (size_t)j*4) = z; }
      continue;
    }
    j -= U2;
    if (j < U3){
      int e0 = j*4;
      for (int e = 0; e < 4; ++e) biasp[e0+e] = bih[e0+e] + bhh[e0+e];
      continue;
    }
    j -= U3;
    if (j < U4){
      int elem = j*4;
      int s = elem >> 16;             // /65536
      int rem = elem & 65535;
      int r = rem >> 9;
      int k = rem & 511;
      const float* src;
      if (s == 0) src = images + (size_t)sortp[r]*512 + k;
      else {
        int cap = captions[sortp[r]*20 + (s-1)];
        src = emb + (size_t)cap*512 + k;
      }
      f32x4 v = *reinterpret_cast<const f32x4*>(src);
      u16x4 o;
      o[0]=f2bf(v[0]); o[1]=f2bf(v[1]); o[2]=f2bf(v[2]); o[3]=f2bf(v[3]);
      *reinterpret_cast<u16x4*>(xseq + (size_t)j*4) = o;
      continue;
    }
    j -= U4;
    if (j < U5){ u16x4 z = {0,0,0,0}; *reinterpret_cast<u16x4*>(hseq + (size_t)j*4) = z; continue; }
    j -= U5;
    { // hloc slot 0 per XCD: hloc[x][0][16][512]
      int e0 = j*4;
      int x = e0 >> 13;               // /8192 (16*512)
      int rem = e0 & 8191;
      u16x4 z = {0,0,0,0};
      *reinterpret_cast<u16x4*>(hloc + (size_t)x*172032 + rem) = z;  // 21*16*512 per XCD
    }
  }
}

// ---------------- K3: merged persistent LSTM chain + overlapped FC ----------------
// 1776 blocks x 256 threads, ~35 KB union LDS -> 3 blocks/CU (1 lstm + 2 fc).
// Blocks 0..255: lstm (dispatch first -> co-resident; claim slot by runtime XCC_ID).
// Blocks 256+: fc; block for time t spins on fcflag until all XCDs with unmasked rows
// have published h slot t+2 (agent-scope atomic mirrors, drained before flag stores).
union ShMem {
  struct {
    float pgh[4][4][16][17];          // 17.4 KB h-partials
    float pgx[4][4][16][17];          // 17.4 KB x-partials (next step)
    unsigned short mbuf[16][16];      // h tile for mirror packing
    int s_xw;
  } l;
  unsigned short arena[2][2][4096];   // fc: [buf][A=0/B=1][128*32] = 32 KB
};

__global__ __launch_bounds__(256) void chain_fc(
    const unsigned short* __restrict__ xseq, const unsigned short* __restrict__ wih,
    const unsigned short* __restrict__ whh, const float* __restrict__ biasp,
    unsigned short* __restrict__ hseq, unsigned short* __restrict__ hloc,
    const unsigned short* __restrict__ fcwb, const float* __restrict__ fcb,
    const int* __restrict__ nact, unsigned int* __restrict__ claimc,
    unsigned int* __restrict__ flags, unsigned int* __restrict__ fcflag,
    float* __restrict__ out)
{
  __shared__ ShMem sh;
  const int tid = threadIdx.x;
  const int bid = blockIdx.x;
  const int lane = tid & 63;

  if (bid < 256){
    // ================= LSTM role =================
    if (tid == 0){
      unsigned xcc;
      asm volatile("s_getreg_b32 %0, hwreg(20, 0, 4)" : "=s"(xcc));  // HW_REG_XCC_ID
      int x = (int)(xcc & 7u);
      unsigned slot = __hip_atomic_fetch_add(claimc + x*64, 1u,
                        __ATOMIC_RELAXED, __HIP_MEMORY_SCOPE_AGENT);
      sh.l.s_xw = (x << 8) | (int)(slot & 255u);
    }
    __syncthreads();
    const int x = sh.l.s_xw >> 8;
    const int w = sh.l.s_xw & 255;
    if (w >= 32) return;
    const int R0 = x*16;
    const int C0 = w*16;
    unsigned int* myflags = flags + x*64;

    const int kk  = tid >> 6;                 // wave = k-quarter
    const int fr  = lane & 15;
    const int fkq = (lane >> 4) * 8;
    const int rr  = (lane >> 4) * 4;

    // step-invariant B fragments in registers
    s16x8 BI[4][4], BH[4][4];
    #pragma unroll
    for (int q = 0; q < 4; ++q)
      #pragma unroll
      for (int i = 0; i < 4; ++i){
        size_t off = (size_t)(q*512 + C0 + fr)*512 + kk*128 + i*32 + fkq;
        BI[q][i] = ld8(wih + off);
        BH[q][i] = ld8(whh + off);
      }

    unsigned short* hl = hloc + (size_t)x*172032;   // [21][16][512]
    const int prow = tid >> 4;
    const int pcol = tid & 15;
    const float bz0 = biasp[       C0 + pcol];
    const float bz1 = biasp[ 512 + C0 + pcol];
    const float bz2 = biasp[1024 + C0 + pcol];
    const float bz3 = biasp[1536 + C0 + pcol];
    float creg = 0.f;

    // prologue: x-partials for step 0
    {
      s16x8 ax[4];
      #pragma unroll
      for (int i = 0; i < 4; ++i)
        ax[i] = ld8(xseq + (R0 + fr)*512 + kk*128 + i*32 + fkq);
      #pragma unroll
      for (int q = 0; q < 4; ++q){
        f32x4 accx = (f32x4){0.f,0.f,0.f,0.f};
        #pragma unroll
        for (int i = 0; i < 4; ++i)
          accx = MFMA16(ax[i], BI[q][i], accx);
        #pragma unroll
        for (int p = 0; p < 4; ++p)
          sh.l.pgx[kk][q][rr + p][fr] = accx[p];
      }
    }
    __syncthreads();

    for (int s = 0; s < 20; ++s){
      if (R0 >= nact[s]) break;
      const unsigned short* hp = hl + (size_t)s*8192;

      s16x8 ah[4];
      #pragma unroll
      for (int i = 0; i < 4; ++i)
        ah[i] = ld8(hp + fr*512 + kk*128 + i*32 + fkq);
      #pragma unroll
      for (int q = 0; q < 4; ++q){
        f32x4 acch = (f32x4){0.f,0.f,0.f,0.f};
        #pragma unroll
        for (int i = 0; i < 4; ++i)
          acch = MFMA16(ah[i], BH[q][i], acch);
        #pragma unroll
        for (int p = 0; p < 4; ++p)
          sh.l.pgh[kk][q][rr + p][fr] = acch[p];
      }
      __syncthreads();   // (A)

      {
        float iv = sh.l.pgh[0][0][prow][pcol] + sh.l.pgh[1][0][prow][pcol]
                 + sh.l.pgh[2][0][prow][pcol] + sh.l.pgh[3][0][prow][pcol]
                 + sh.l.pgx[0][0][prow][pcol] + sh.l.pgx[1][0][prow][pcol]
                 + sh.l.pgx[2][0][prow][pcol] + sh.l.pgx[3][0][prow][pcol] + bz0;
        float fv = sh.l.pgh[0][1][prow][pcol] + sh.l.pgh[1][1][prow][pcol]
                 + sh.l.pgh[2][1][prow][pcol] + sh.l.pgh[3][1][prow][pcol]
                 + sh.l.pgx[0][1][prow][pcol] + sh.l.pgx[1][1][prow][pcol]
                 + sh.l.pgx[2][1][prow][pcol] + sh.l.pgx[3][1][prow][pcol] + bz1;
        float gv = sh.l.pgh[0][2][prow][pcol] + sh.l.pgh[1][2][prow][pcol]
                 + sh.l.pgh[2][2][prow][pcol] + sh.l.pgh[3][2][prow][pcol]
                 + sh.l.pgx[0][2][prow][pcol] + sh.l.pgx[1][2][prow][pcol]
                 + sh.l.pgx[2][2][prow][pcol] + sh.l.pgx[3][2][prow][pcol] + bz2;
        float ov = sh.l.pgh[0][3][prow][pcol] + sh.l.pgh[1][3][prow][pcol]
                 + sh.l.pgh[2][3][prow][pcol] + sh.l.pgh[3][3][prow][pcol]
                 + sh.l.pgx[0][3][prow][pcol] + sh.l.pgx[1][3][prow][pcol]
                 + sh.l.pgx[2][3][prow][pcol] + sh.l.pgx[3][3][prow][pcol] + bz3;
        creg = sigf(fv)*creg + sigf(iv)*tanh_(gv);
        float h = sigf(ov)*tanh_(creg);
        unsigned short hb = f2bf(h);
        hl[(size_t)(s+1)*8192 + prow*512 + C0 + pcol] = hb;   // XCD-local publish
        sh.l.mbuf[prow][pcol] = hb;
      }
      __syncthreads();   // (B) drains hl stores; mbuf visible

      // mirror to canonical hseq at the coherent point (agent atomics)
      if (tid < 128){
        int r  = tid >> 3;
        int c2 = (tid & 7) * 2;
        unsigned wrd = (unsigned)sh.l.mbuf[r][c2] | ((unsigned)sh.l.mbuf[r][c2+1] << 16);
        __hip_atomic_exchange(reinterpret_cast<unsigned*>(
            hseq + (size_t)(s+1)*65536 + (size_t)(R0 + r)*512 + C0 + c2),
            wrd, __ATOMIC_RELAXED, __HIP_MEMORY_SCOPE_AGENT);
      }
      __syncthreads();   // (D) drains mirror atomics -> flag implies mirror visible

      {
        const unsigned tgt = (unsigned)(s + 1);
        if (tid == 0)
          __hip_atomic_store(&myflags[w], tgt, __ATOMIC_RELAXED, __HIP_MEMORY_SCOPE_AGENT);

        // x-partials for step s+1 inside the barrier window
        if (s < 19 && nact[s+1] > R0){
          const unsigned short* xp = xseq + (size_t)(s+1)*65536;
          s16x8 ax[4];
          #pragma unroll
          for (int i = 0; i < 4; ++i)
            ax[i] = ld8(xp + (R0 + fr)*512 + kk*128 + i*32 + fkq);
          #pragma unroll
          for (int q = 0; q < 4; ++q){
            f32x4 accx = (f32x4){0.f,0.f,0.f,0.f};
            #pragma unroll
            for (int i = 0; i < 4; ++i)
              accx = MFMA16(ax[i], BI[q][i], accx);
            #pragma unroll
            for (int p = 0; p < 4; ++p)
              sh.l.pgx[kk][q][rr + p][fr] = accx[p];
          }
        }

        if (tid < 64){
          long guard = 0;
          for (;;){
            bool ok = true;
            if (tid < 32)
              ok = (__hip_atomic_load(&myflags[tid], __ATOMIC_RELAXED,
                                      __HIP_MEMORY_SCOPE_AGENT) >= tgt);
            if (__all(ok) || ++guard > (1L << 20)) break;
            __builtin_amdgcn_s_sleep(1);
          }
        }
        // leader publishes XCD progress for fc (poll-complete => peers' mirrors drained)
        if (tid == 0 && w == 0)
          __hip_atomic_store(&fcflag[x*16], tgt, __ATOMIC_RELAXED, __HIP_MEMORY_SCOPE_AGENT);
        __syncthreads();   // (C)
      }
    }
    return;
  }

  // ================= FC role =================
  const int bfc  = bid - 256;
  const int slot = bfc >> 3;
  const int xaff = bfc & 7;
  const int t    = slot % 19;
  const int p    = xaff + 8*(slot/19);
  if (p >= 79) return;
  const int v0   = p * 128;
  const int n_t  = nact[t + 1];

  const unsigned short* Ag = hseq + (size_t)(t + 2)*65536;   // h_{t+1}: 128 x 512
  const unsigned short* Bg = fcwb + (size_t)v0*512;          // panel: 128 x 512

  const int srow = tid >> 2;          // 0..63
  const int sphy = tid & 3;
  const int wuni = (tid >> 6) << 9;   // wave*512 shorts

  #define AbF(c) (&sh.arena[c][0][0])
  #define BbF(c) (&sh.arena[c][1][0])
  #define STAGE(gsrc, lbuf, kt)                                               \
    _Pragma("unroll")                                                         \
    for (int call = 0; call < 2; ++call){                                     \
      int row_ = call*64 + srow;                                              \
      gload_lds16(gsrc + (size_t)row_*512 + (kt)*32 + ((sphy ^ (row_ & 3)) << 3), \
                  lbuf + call*2048 + wuni);                                   \
    }

  // prefetch B tile 0 (independent of h), then wait for h slot t+2
  STAGE(Bg, BbF(0), 0)
  {
    if (tid < 64){
      long guard = 0;
      for (;;){
        bool ok = true;
        if (tid < 8){
          unsigned f = __hip_atomic_load(&fcflag[tid*16], __ATOMIC_RELAXED,
                                         __HIP_MEMORY_SCOPE_AGENT);
          ok = (f >= (unsigned)(t + 2)) || (n_t <= tid*16);
        }
        if (__all(ok) || ++guard > (1L << 20)) break;
        __builtin_amdgcn_s_sleep(8);
      }
    }
    __syncthreads();
  }

  const int wv = tid >> 6;
  const int wr = wv >> 1, wc = wv & 1;
  const int fr = lane & 15;
  const int hi = lane >> 4;           // 0..3 (k-slot)

  f32x4 acc[4][4];
  #pragma unroll
  for (int i = 0; i < 4; ++i)
    #pragma unroll
    for (int j = 0; j < 4; ++j)
      acc[i][j] = (f32x4){0.f,0.f,0.f,0.f};

  STAGE(Ag, AbF(0), 0)
  STAGE(Ag, AbF(1), 1)
  STAGE(Bg, BbF(1), 1)
  asm volatile("s_waitcnt vmcnt(0)" ::: "memory");
  __syncthreads();

  int cur = 0;
  for (int kt = 0; kt < 16; ++kt){
    if (kt < 14){
      STAGE(Ag, AbF(cur), kt+2)     // overwrite after compute? no: staged into cur AFTER compute consumes cur this iter -> must stage into buffer being freed NEXT iter
    }
    // NOTE: correct 2-deep schedule below — compute cur, then restage cur for kt+2
    const unsigned short* As = AbF(cur);
    const unsigned short* Bs = BbF(cur);
    s16x8 af[4], bf[4];
    #pragma unroll
    for (int i = 0; i < 4; ++i){
      int row = wr*64 + i*16 + fr;
      af[i] = ld8(As + row*32 + ((hi ^ (row & 3)) << 3));
    }
    #pragma unroll
    for (int j = 0; j < 4; ++j){
      int col = wc*64 + j*16 + fr;
      bf[j] = ld8(Bs + col*32 + ((hi ^ (col & 3)) << 3));
    }
    #pragma unroll
    for (int i = 0; i < 4; ++i)
      #pragma unroll
      for (int j = 0; j < 4; ++j)
        acc[i][j] = MFMA16(af[i], bf[j], acc[i][j]);
    if (kt < 14){
      STAGE(Bg, BbF(cur), kt+2)
    }
    asm volatile("s_waitcnt vmcnt(0)" ::: "memory");
    __syncthreads();
    cur ^= 1;
  }

  const int rr2 = hi * 4;
  #pragma unroll
  for (int j = 0; j < 4; ++j){
    int v = v0 + wc*64 + j*16 + fr;
    if (v >= 10000) continue;
    float bb = fcb[v];
    #pragma unroll
    for (int i = 0; i < 4; ++i){
      #pragma unroll
      for (int pp = 0; pp < 4; ++pp){
        int r = wr*64 + i*16 + rr2 + pp;
        out[(size_t)(r*19 + t)*10000 + v] = (r < n_t) ? (acc[i][j][pp] + bb) : 0.0f;
      }
    }
  }
  #undef STAGE
  #undef AbF
  #undef BbF
}

extern "C" void kernel_launch(void* const* d_in, const int* in_sizes, int n_in,
                              void* d_out, int out_size, void* d_ws, size_t ws_size,
                              hipStream_t stream) {
  const float* images   = (const float*)d_in[0];
  const int*   captions = (const int*)  d_in[1];
  const int*   length   = (const int*)  d_in[2];
  const float* emb      = (const float*)d_in[3];
  const float* W_ih     = (const float*)d_in[4];
  const float* W_hh     = (const float*)d_in[5];
  const float* b_ih     = (const float*)d_in[6];
  const float* b_hh     = (const float*)d_in[7];
  const float* fc_w     = (const float*)d_in[8];
  const float* fc_b     = (const float*)d_in[9];
  float* out = (float*)d_out;
  char*  ws  = (char*)d_ws;

  int*            sortp  = (int*)           (ws + 0);
  int*            nactp  = (int*)           (ws + 2048);
  float*          biasp  = (float*)         (ws + 4096);
  unsigned int*   cnt4k  = (unsigned int*)  (ws + 12288);     // claim[8] + flags[8][32] + fcflag[8]
  unsigned int*   claimc = cnt4k;                              // claimc + x*64
  unsigned int*   flags  = cnt4k + 512;                        // flags + x*64 + w
  unsigned int*   fcflag = cnt4k + 768;                        // fcflag + x*16
  unsigned short* hloc   = (unsigned short*)(ws + 16384);      // 8 x [21][16][512] bf16
  unsigned short* hseq   = (unsigned short*)(ws + 2768896);    // canonical 21 x 128 x 512 bf16
  unsigned short* xseq   = (unsigned short*)(ws + 5521408);    // 20 slots
  unsigned short* wihb   = (unsigned short*)(ws + 8142848);
  unsigned short* whhb   = (unsigned short*)(ws + 10240000);
  unsigned short* fcwb   = (unsigned short*)(ws + 12337152);   // 10112x512 bf16, ends ~22.7 MB

  k0_sort<<<1, 128, 0, stream>>>(length, captions, out, sortp, nactp, cnt4k);
  k1_convert<<<4096, 256, 0, stream>>>(images, captions, emb, W_ih, W_hh, b_ih, b_hh,
                                       fc_w, sortp, wihb, whhb, fcwb, biasp, xseq, hseq, hloc);
  chain_fc<<<1776, 256, 0, stream>>>(xseq, wihb, whhb, biasp, hseq, hloc,
                                     fcwb, fc_b, nactp, claimc, flags, fcflag, out);
}